// Round 12
// baseline (836.900 us; speedup 1.0000x reference)
//
#include <hip/hip_runtime.h>
#include <math.h>

// kmeans assign = GEMM X[1M x 50] . Phi^T[50 x 256] with fused argmin epilogue.
// R11 (validated, absmax=0): 234us, MfmaUtil 17.6%, VALUBusy 50%, Occ 33% -> VALU-issue +
// occupancy bound. R12: (1) 33KB LDS (two-phase B staging + p2 in LDS) -> 4 blocks/CU,
// lb(512,8) caps VGPR at 64 -> target 32 waves/CU; (2) packed-u32 argmin: score biased
// positive (+256 folded into p2b), idx in low 8 bits, sorted-pair min/max/min.
// Pack err <= 2^8 ulp(512) ~ 0.016; total approx err ~0.018 < TAU/2 -> margin gate sound.
// Rows with packed margin < TAU=0.05 rescreened exactly (validated f32 path, jnp tie rule).
#define NPTS 1000000
#define DIM 50
#define NC 256
#define TAU 0.05f
#define MR 2
#define NTILES (NPTS / (MR * 16))   // 31250 wave-tiles of 32 rows

typedef short bf16x8 __attribute__((ext_vector_type(8)));   // 8 bf16 (4 VGPRs)
typedef float f32x4 __attribute__((ext_vector_type(4)));    // 4 fp32 acc

__device__ __forceinline__ short f2bf(float f) {            // f32 -> bf16 RN-even
    unsigned u = __builtin_bit_cast(unsigned, f);
    unsigned r = (u + 0x7FFFu + ((u >> 16) & 1u)) >> 16;
    return (short)r;
}
__device__ __forceinline__ float bf2f(short h) {
    unsigned u = ((unsigned)(unsigned short)h) << 16;
    return __builtin_bit_cast(float, u);
}
__device__ __forceinline__ void cvt8(const float* v, bf16x8& hi, bf16x8& lo) {
#pragma unroll
    for (int j = 0; j < 8; ++j) {
        short h = f2bf(v[j]);
        hi[j] = h;
        lo[j] = f2bf(v[j] - bf2f(h));
    }
}

// ws layout: [0,64KB) Phi frag [ct(16)][ks(2)][split(2)][lane(64)][8 shorts]
//            [64KB,+1KB) p2 plain (exact rescreen)   [65KB,+1KB) p2b = 256+p2 (packed path)
__global__ void __launch_bounds__(256) prep_kernel(const float* __restrict__ Phi,
                                                   short* __restrict__ frag,
                                                   float* __restrict__ p2,
                                                   float* __restrict__ p2b) {
    int tid = threadIdx.x;
    {
        const float* p = Phi + tid * DIM;
        float s = 0.f;
#pragma unroll
        for (int d = 0; d < DIM; ++d) s = fmaf(p[d], p[d], s);
        p2[tid] = s;
        p2b[tid] = 256.0f + s;
    }
    for (int it = tid; it < 4096; it += 256) {
        int lane = it & 63;
        int rest = it >> 6;
        int split = rest & 1;
        int ks = (rest >> 1) & 1;
        int ct = rest >> 2;
        int col = lane & 15;
        int kb = ks * 32 + ((lane >> 4) << 3);
        const float* pr = Phi + (ct * 16 + col) * DIM;
        short* dst = frag + (size_t)it * 8;
#pragma unroll
        for (int j = 0; j < 8; ++j) {
            int k = kb + j;
            float v = (k < DIM) ? pr[k] : 0.f;
            short h = f2bf(v);
            dst[j] = (split == 0) ? h : f2bf(v - bf2f(h));
        }
    }
}

// Exact f32 rescreen for one row: identical math/tie-break to the validated scalar kernel.
__device__ void exact_row(const float* __restrict__ X, const float* __restrict__ Phi,
                          const float* __restrict__ p2, int* __restrict__ out, int row) {
    int lane = threadIdx.x & 63;
    const float* xr = X + (size_t)row * DIM;
    float x2 = 0.f;
#pragma unroll
    for (int d = 0; d < DIM; ++d) x2 = fmaf(xr[d], xr[d], x2);
    float best = INFINITY;
    int bi = 0;
    for (int i = 0; i < 4; ++i) {
        int c = lane * 4 + i;                 // within-lane ascending c; strict <
        const float* pr = Phi + c * DIM;
        float a = 0.f;
#pragma unroll
        for (int d = 0; d < DIM; ++d) a = fmaf(xr[d], pr[d], a);
        float sc = (x2 + p2[c]) - 2.0f * a;   // reference rounding order
        if (sc < best) { best = sc; bi = c; }
    }
#pragma unroll
    for (int m = 1; m < 64; m <<= 1) {        // cross-lane: lower idx wins ties
        float ob = __shfl_xor(best, m);
        int oi = __shfl_xor(bi, m);
        if (ob < best || (ob == best && oi < bi)) { best = ob; bi = oi; }
    }
    if (lane == 0) out[row] = bi;
}

__global__ void __launch_bounds__(512, 8) assign_kernel(const float* __restrict__ X,
                                                        const float* __restrict__ Phi,
                                                        const int4* __restrict__ BfI,
                                                        const float* __restrict__ p2,
                                                        const float* __restrict__ p2b,
                                                        int* __restrict__ out) {
    __shared__ int4 Bs[2048];    // 32 KB: half the B frags (8 col-tiles) per phase
    __shared__ float P2s[256];   // 1 KB: biased p2

    int tid = threadIdx.x;
    int lane = tid & 63;
    int wid = tid >> 6;
    int t = blockIdx.x * 8 + wid;              // wave tile id: 32 rows each
    bool active = (t < NTILES);
    int tbase = t * (MR * 16);
    int colRow = lane & 15;                    // A: row-within-16; C: col-within-16
    int kgrp = lane >> 4;
    const bf16x8* Bsf = (const bf16x8*)Bs;

    // ---- Stage phase-0 B frags + p2b (all threads; barriers outside `active`) ----
#pragma unroll
    for (int j = 0; j < 4; ++j)
        Bs[tid + j * 512] = BfI[tid + j * 512];
    if (tid < 256) P2s[tid] = p2b[tid];

    // ---- A-frag load + split (validated R11 path) ----
    bf16x8 Ahi[MR][2], Alo[MR][2];
    unsigned pm1[MR][4], pm2[MR][4];
    if (active) {
#pragma unroll
        for (int mr = 0; mr < MR; ++mr) {
            const float* xp = X + (size_t)(tbase + mr * 16 + colRow) * DIM;
            {   // ks=0: k in [kgrp*8, kgrp*8+8) <= 39 < 50
                float v[8];
                const float2* q = (const float2*)(xp + (kgrp << 3));
#pragma unroll
                for (int h = 0; h < 4; ++h) { float2 e = q[h]; v[2 * h] = e.x; v[2 * h + 1] = e.y; }
                cvt8(v, Ahi[mr][0], Alo[mr][0]);
            }
            {   // ks=1: o = 32+kgrp*8+2h; clamp load in-row, mask o>48
                float v[8];
#pragma unroll
                for (int h = 0; h < 4; ++h) {
                    int o = 32 + (kgrp << 3) + 2 * h;
                    int oc = (o <= 48) ? o : 48;
                    float2 e = *(const float2*)(xp + oc);
                    bool valid = (o <= 48);
                    v[2 * h]     = valid ? e.x : 0.f;
                    v[2 * h + 1] = valid ? e.y : 0.f;
                }
                cvt8(v, Ahi[mr][1], Alo[mr][1]);
            }
        }
#pragma unroll
        for (int mr = 0; mr < MR; ++mr)
#pragma unroll
            for (int r = 0; r < 4; ++r) { pm1[mr][r] = 0xFFFFFFFFu; pm2[mr][r] = 0xFFFFFFFFu; }
    }

    // ---- Per-phase 8-ct loop: scores packed (score&~255 | idx), sorted-pair min ----
    auto process8 = [&](int phase) {
#pragma unroll 2
        for (int c8 = 0; c8 < 8; ++c8) {
            int ct = phase * 8 + c8;
            bf16x8 b0h = Bsf[(c8 * 4 + 0) * 64 + lane];
            bf16x8 b0l = Bsf[(c8 * 4 + 1) * 64 + lane];
            bf16x8 b1h = Bsf[(c8 * 4 + 2) * 64 + lane];
            bf16x8 b1l = Bsf[(c8 * 4 + 3) * 64 + lane];
            float p2v = P2s[ct * 16 + colRow];
            unsigned vidx = (unsigned)(ct * 16 + colRow);
#pragma unroll
            for (int mr = 0; mr < MR; ++mr) {
                f32x4 acc = {0.f, 0.f, 0.f, 0.f};
                acc = __builtin_amdgcn_mfma_f32_16x16x32_bf16(Alo[mr][0], b0h, acc, 0, 0, 0);
                acc = __builtin_amdgcn_mfma_f32_16x16x32_bf16(Ahi[mr][0], b0l, acc, 0, 0, 0);
                acc = __builtin_amdgcn_mfma_f32_16x16x32_bf16(Ahi[mr][0], b0h, acc, 0, 0, 0);
                acc = __builtin_amdgcn_mfma_f32_16x16x32_bf16(Alo[mr][1], b1h, acc, 0, 0, 0);
                acc = __builtin_amdgcn_mfma_f32_16x16x32_bf16(Ahi[mr][1], b1l, acc, 0, 0, 0);
                acc = __builtin_amdgcn_mfma_f32_16x16x32_bf16(Ahi[mr][1], b1h, acc, 0, 0, 0);
#pragma unroll
                for (int r = 0; r < 4; ++r) {
                    float sc = fmaf(-2.0f, acc[r], p2v);          // positive: bias 256
                    unsigned u = (__builtin_bit_cast(unsigned, sc) & ~255u) | vidx;
                    unsigned u2 = max(pm1[mr][r], u);             // old pm1
                    pm2[mr][r] = min(pm2[mr][r], u2);
                    pm1[mr][r] = min(pm1[mr][r], u);
                }
            }
        }
    };

    __syncthreads();
    if (active) process8(0);
    __syncthreads();
#pragma unroll
    for (int j = 0; j < 4; ++j)
        Bs[tid + j * 512] = BfI[2048 + tid + j * 512];
    __syncthreads();
    if (active) process8(1);

    // ---- Epilogue: merge sorted pairs across the 16-lane group; store or rescreen ----
    if (active) {
#pragma unroll
        for (int mr = 0; mr < MR; ++mr) {
#pragma unroll
            for (int r = 0; r < 4; ++r) {
                unsigned a1 = pm1[mr][r], a2 = pm2[mr][r];
#pragma unroll
                for (int m = 1; m <= 8; m <<= 1) {
                    unsigned b1 = (unsigned)__shfl_xor((int)a1, m);
                    unsigned b2 = (unsigned)__shfl_xor((int)a2, m);
                    a2 = min(min(a2, b2), max(a1, b1));
                    a1 = min(a1, b1);
                }
                float f1 = __builtin_bit_cast(float, a1 & ~255u);
                float f2 = __builtin_bit_cast(float, a2 & ~255u);
                bool flag = (f2 - f1) < TAU;          // uniform across the group
                int bi = (int)(a1 & 255u);
                if ((lane & 15) == 0 && !flag)
                    out[tbase + mr * 16 + (lane >> 4) * 4 + r] = bi;
                unsigned long long mb = __ballot(flag) & 0x0001000100010001ULL;
                while (mb) {                           // ~0.8% of rows: exact rescreen
                    int g = __builtin_ctzll(mb) >> 4;
                    mb &= mb - 1;
                    exact_row(X, Phi, p2, out, tbase + mr * 16 + g * 4 + r);
                }
            }
        }
    }
}

extern "C" void kernel_launch(void* const* d_in, const int* in_sizes, int n_in,
                              void* d_out, int out_size, void* d_ws, size_t ws_size,
                              hipStream_t stream) {
    const float* X   = (const float*)d_in[0];
    const float* Phi = (const float*)d_in[1];
    int* out   = (int*)d_out;
    short* frag = (short*)d_ws;                         // 64 KB
    float* p2   = (float*)((char*)d_ws + 65536);        // 1 KB plain
    float* p2b  = (float*)((char*)d_ws + 65536 + 1024); // 1 KB biased

    prep_kernel<<<1, 256, 0, stream>>>(Phi, frag, p2, p2b);
    int nblk = (NTILES + 7) / 8;                        // 3907 blocks x 512 threads
    assign_kernel<<<nblk, 512, 0, stream>>>(X, Phi, (const int4*)frag, p2, p2b, out);
}

// Round 13
// 394.429 us; speedup vs baseline: 2.1218x; 2.1218x over previous
//
#include <hip/hip_runtime.h>
#include <math.h>

// kmeans assign = GEMM X[1M x 50] . Phi^T[50 x 256] with fused argmin epilogue.
// R11 (validated): 234us, Occ 33%, VGPR 64, no spill. R12: lb(512,8) forced VGPR->32,
// spilled A-frags/argmin to scratch (WRITE_SIZE 826MB, 641us). R13: revert ONLY the
// bound to lb(512,4) (VGPR cap 128; R11's allocator chose 64 under it). Keep R12's
// two-phase 33KB LDS staging (4 blocks/CU possible) + packed-u32 argmin (score&~255|idx,
// bias +256 via p2b; pack err ~0.016, total ~0.018 < TAU/2 -> margin gate sound).
// Rows with packed margin < TAU=0.05 rescreened exactly (validated f32 path, jnp tie rule).
#define NPTS 1000000
#define DIM 50
#define NC 256
#define TAU 0.05f
#define MR 2
#define NTILES (NPTS / (MR * 16))   // 31250 wave-tiles of 32 rows

typedef short bf16x8 __attribute__((ext_vector_type(8)));   // 8 bf16 (4 VGPRs)
typedef float f32x4 __attribute__((ext_vector_type(4)));    // 4 fp32 acc

__device__ __forceinline__ short f2bf(float f) {            // f32 -> bf16 RN-even
    unsigned u = __builtin_bit_cast(unsigned, f);
    unsigned r = (u + 0x7FFFu + ((u >> 16) & 1u)) >> 16;
    return (short)r;
}
__device__ __forceinline__ float bf2f(short h) {
    unsigned u = ((unsigned)(unsigned short)h) << 16;
    return __builtin_bit_cast(float, u);
}
__device__ __forceinline__ void cvt8(const float* v, bf16x8& hi, bf16x8& lo) {
#pragma unroll
    for (int j = 0; j < 8; ++j) {
        short h = f2bf(v[j]);
        hi[j] = h;
        lo[j] = f2bf(v[j] - bf2f(h));
    }
}

// ws layout: [0,64KB) Phi frag [ct(16)][ks(2)][split(2)][lane(64)][8 shorts]
//            [64KB,+1KB) p2 plain (exact rescreen)   [65KB,+1KB) p2b = 256+p2 (packed path)
__global__ void __launch_bounds__(256) prep_kernel(const float* __restrict__ Phi,
                                                   short* __restrict__ frag,
                                                   float* __restrict__ p2,
                                                   float* __restrict__ p2b) {
    int tid = threadIdx.x;
    {
        const float* p = Phi + tid * DIM;
        float s = 0.f;
#pragma unroll
        for (int d = 0; d < DIM; ++d) s = fmaf(p[d], p[d], s);
        p2[tid] = s;
        p2b[tid] = 256.0f + s;
    }
    for (int it = tid; it < 4096; it += 256) {
        int lane = it & 63;
        int rest = it >> 6;
        int split = rest & 1;
        int ks = (rest >> 1) & 1;
        int ct = rest >> 2;
        int col = lane & 15;
        int kb = ks * 32 + ((lane >> 4) << 3);
        const float* pr = Phi + (ct * 16 + col) * DIM;
        short* dst = frag + (size_t)it * 8;
#pragma unroll
        for (int j = 0; j < 8; ++j) {
            int k = kb + j;
            float v = (k < DIM) ? pr[k] : 0.f;
            short h = f2bf(v);
            dst[j] = (split == 0) ? h : f2bf(v - bf2f(h));
        }
    }
}

// Exact f32 rescreen for one row: identical math/tie-break to the validated scalar kernel.
__device__ void exact_row(const float* __restrict__ X, const float* __restrict__ Phi,
                          const float* __restrict__ p2, int* __restrict__ out, int row) {
    int lane = threadIdx.x & 63;
    const float* xr = X + (size_t)row * DIM;
    float x2 = 0.f;
#pragma unroll
    for (int d = 0; d < DIM; ++d) x2 = fmaf(xr[d], xr[d], x2);
    float best = INFINITY;
    int bi = 0;
    for (int i = 0; i < 4; ++i) {
        int c = lane * 4 + i;                 // within-lane ascending c; strict <
        const float* pr = Phi + c * DIM;
        float a = 0.f;
#pragma unroll
        for (int d = 0; d < DIM; ++d) a = fmaf(xr[d], pr[d], a);
        float sc = (x2 + p2[c]) - 2.0f * a;   // reference rounding order
        if (sc < best) { best = sc; bi = c; }
    }
#pragma unroll
    for (int m = 1; m < 64; m <<= 1) {        // cross-lane: lower idx wins ties
        float ob = __shfl_xor(best, m);
        int oi = __shfl_xor(bi, m);
        if (ob < best || (ob == best && oi < bi)) { best = ob; bi = oi; }
    }
    if (lane == 0) out[row] = bi;
}

__global__ void __launch_bounds__(512, 4) assign_kernel(const float* __restrict__ X,
                                                        const float* __restrict__ Phi,
                                                        const int4* __restrict__ BfI,
                                                        const float* __restrict__ p2,
                                                        const float* __restrict__ p2b,
                                                        int* __restrict__ out) {
    __shared__ int4 Bs[2048];    // 32 KB: half the B frags (8 col-tiles) per phase
    __shared__ float P2s[256];   // 1 KB: biased p2

    int tid = threadIdx.x;
    int lane = tid & 63;
    int wid = tid >> 6;
    int t = blockIdx.x * 8 + wid;              // wave tile id: 32 rows each
    bool active = (t < NTILES);
    int tbase = t * (MR * 16);
    int colRow = lane & 15;                    // A: row-within-16; C: col-within-16
    int kgrp = lane >> 4;
    const bf16x8* Bsf = (const bf16x8*)Bs;

    // ---- Stage phase-0 B frags + p2b (all threads; barriers outside `active`) ----
#pragma unroll
    for (int j = 0; j < 4; ++j)
        Bs[tid + j * 512] = BfI[tid + j * 512];
    if (tid < 256) P2s[tid] = p2b[tid];

    // ---- A-frag load + split (validated R11 path) ----
    bf16x8 Ahi[MR][2], Alo[MR][2];
    unsigned pm1[MR][4], pm2[MR][4];
    if (active) {
#pragma unroll
        for (int mr = 0; mr < MR; ++mr) {
            const float* xp = X + (size_t)(tbase + mr * 16 + colRow) * DIM;
            {   // ks=0: k in [kgrp*8, kgrp*8+8) <= 39 < 50
                float v[8];
                const float2* q = (const float2*)(xp + (kgrp << 3));
#pragma unroll
                for (int h = 0; h < 4; ++h) { float2 e = q[h]; v[2 * h] = e.x; v[2 * h + 1] = e.y; }
                cvt8(v, Ahi[mr][0], Alo[mr][0]);
            }
            {   // ks=1: o = 32+kgrp*8+2h; clamp load in-row, mask o>48
                float v[8];
#pragma unroll
                for (int h = 0; h < 4; ++h) {
                    int o = 32 + (kgrp << 3) + 2 * h;
                    int oc = (o <= 48) ? o : 48;
                    float2 e = *(const float2*)(xp + oc);
                    bool valid = (o <= 48);
                    v[2 * h]     = valid ? e.x : 0.f;
                    v[2 * h + 1] = valid ? e.y : 0.f;
                }
                cvt8(v, Ahi[mr][1], Alo[mr][1]);
            }
        }
#pragma unroll
        for (int mr = 0; mr < MR; ++mr)
#pragma unroll
            for (int r = 0; r < 4; ++r) { pm1[mr][r] = 0xFFFFFFFFu; pm2[mr][r] = 0xFFFFFFFFu; }
    }

    // ---- Per-phase 8-ct loop: scores packed (score&~255 | idx), sorted-pair min ----
    auto process8 = [&](int phase) {
#pragma unroll 2
        for (int c8 = 0; c8 < 8; ++c8) {
            int ct = phase * 8 + c8;
            bf16x8 b0h = Bsf[(c8 * 4 + 0) * 64 + lane];
            bf16x8 b0l = Bsf[(c8 * 4 + 1) * 64 + lane];
            bf16x8 b1h = Bsf[(c8 * 4 + 2) * 64 + lane];
            bf16x8 b1l = Bsf[(c8 * 4 + 3) * 64 + lane];
            float p2v = P2s[ct * 16 + colRow];
            unsigned vidx = (unsigned)(ct * 16 + colRow);
#pragma unroll
            for (int mr = 0; mr < MR; ++mr) {
                f32x4 acc = {0.f, 0.f, 0.f, 0.f};
                acc = __builtin_amdgcn_mfma_f32_16x16x32_bf16(Alo[mr][0], b0h, acc, 0, 0, 0);
                acc = __builtin_amdgcn_mfma_f32_16x16x32_bf16(Ahi[mr][0], b0l, acc, 0, 0, 0);
                acc = __builtin_amdgcn_mfma_f32_16x16x32_bf16(Ahi[mr][0], b0h, acc, 0, 0, 0);
                acc = __builtin_amdgcn_mfma_f32_16x16x32_bf16(Alo[mr][1], b1h, acc, 0, 0, 0);
                acc = __builtin_amdgcn_mfma_f32_16x16x32_bf16(Ahi[mr][1], b1l, acc, 0, 0, 0);
                acc = __builtin_amdgcn_mfma_f32_16x16x32_bf16(Ahi[mr][1], b1h, acc, 0, 0, 0);
#pragma unroll
                for (int r = 0; r < 4; ++r) {
                    float sc = fmaf(-2.0f, acc[r], p2v);          // positive: bias 256
                    unsigned u = (__builtin_bit_cast(unsigned, sc) & ~255u) | vidx;
                    unsigned u2 = max(pm1[mr][r], u);             // old pm1
                    pm2[mr][r] = min(pm2[mr][r], u2);
                    pm1[mr][r] = min(pm1[mr][r], u);
                }
            }
        }
    };

    __syncthreads();
    if (active) process8(0);
    __syncthreads();
#pragma unroll
    for (int j = 0; j < 4; ++j)
        Bs[tid + j * 512] = BfI[2048 + tid + j * 512];
    __syncthreads();
    if (active) process8(1);

    // ---- Epilogue: merge sorted pairs across the 16-lane group; store or rescreen ----
    if (active) {
#pragma unroll
        for (int mr = 0; mr < MR; ++mr) {
#pragma unroll
            for (int r = 0; r < 4; ++r) {
                unsigned a1 = pm1[mr][r], a2 = pm2[mr][r];
#pragma unroll
                for (int m = 1; m <= 8; m <<= 1) {
                    unsigned b1 = (unsigned)__shfl_xor((int)a1, m);
                    unsigned b2 = (unsigned)__shfl_xor((int)a2, m);
                    a2 = min(min(a2, b2), max(a1, b1));
                    a1 = min(a1, b1);
                }
                float f1 = __builtin_bit_cast(float, a1 & ~255u);
                float f2 = __builtin_bit_cast(float, a2 & ~255u);
                bool flag = (f2 - f1) < TAU;          // uniform across the group
                int bi = (int)(a1 & 255u);
                if ((lane & 15) == 0 && !flag)
                    out[tbase + mr * 16 + (lane >> 4) * 4 + r] = bi;
                unsigned long long mb = __ballot(flag) & 0x0001000100010001ULL;
                while (mb) {                           // ~0.8% of rows: exact rescreen
                    int g = __builtin_ctzll(mb) >> 4;
                    mb &= mb - 1;
                    exact_row(X, Phi, p2, out, tbase + mr * 16 + g * 4 + r);
                }
            }
        }
    }
}

extern "C" void kernel_launch(void* const* d_in, const int* in_sizes, int n_in,
                              void* d_out, int out_size, void* d_ws, size_t ws_size,
                              hipStream_t stream) {
    const float* X   = (const float*)d_in[0];
    const float* Phi = (const float*)d_in[1];
    int* out   = (int*)d_out;
    short* frag = (short*)d_ws;                         // 64 KB
    float* p2   = (float*)((char*)d_ws + 65536);        // 1 KB plain
    float* p2b  = (float*)((char*)d_ws + 65536 + 1024); // 1 KB biased

    prep_kernel<<<1, 256, 0, stream>>>(Phi, frag, p2, p2b);
    int nblk = (NTILES + 7) / 8;                        // 3907 blocks x 512 threads
    assign_kernel<<<nblk, 512, 0, stream>>>(X, Phi, (const int4*)frag, p2, p2b, out);
}

// Round 16
// 374.363 us; speedup vs baseline: 2.2355x; 1.0536x over previous
//
#include <hip/hip_runtime.h>
#include <math.h>

// kmeans assign = GEMM X[1M x 50] . Phi^T[50 x 256] with fused argmin epilogue.
// R13 (validated): 190us, VGPR 64 no-spill, MfmaUtil 21%, Occ 30%. Occupancy didn't move
// when LDS halved (R11 64KB->R13 33KB both ~30%), but R4's 256-thr kernel hit 64% ->
// 512-thr workgroups are the residency limiter. R14: 256-thr blocks (4 waves), 4-phase
// B staging (16KB + 1KB p2 = 17.5KB LDS) -> up to 8 blocks/CU = 32 waves/CU.
// Math identical to validated R13: packed-u32 argmin (score&~255|idx, bias +256 via p2b;
// pack err ~0.016 < TAU/2), TAU=0.05 margin gate, exact f32 rescreen (jnp tie rule).
#define NPTS 1000000
#define DIM 50
#define NC 256
#define TAU 0.05f
#define MR 2
#define NTILES (NPTS / (MR * 16))   // 31250 wave-tiles of 32 rows

typedef short bf16x8 __attribute__((ext_vector_type(8)));   // 8 bf16 (4 VGPRs)
typedef float f32x4 __attribute__((ext_vector_type(4)));    // 4 fp32 acc

__device__ __forceinline__ short f2bf(float f) {            // f32 -> bf16 RN-even
    unsigned u = __builtin_bit_cast(unsigned, f);
    unsigned r = (u + 0x7FFFu + ((u >> 16) & 1u)) >> 16;
    return (short)r;
}
__device__ __forceinline__ float bf2f(short h) {
    unsigned u = ((unsigned)(unsigned short)h) << 16;
    return __builtin_bit_cast(float, u);
}
__device__ __forceinline__ void cvt8(const float* v, bf16x8& hi, bf16x8& lo) {
#pragma unroll
    for (int j = 0; j < 8; ++j) {
        short h = f2bf(v[j]);
        hi[j] = h;
        lo[j] = f2bf(v[j] - bf2f(h));
    }
}

// ws layout: [0,64KB) Phi frag [ct(16)][ks(2)][split(2)][lane(64)][8 shorts]
//            [64KB,+1KB) p2 plain (exact rescreen)   [65KB,+1KB) p2b = 256+p2 (packed path)
__global__ void __launch_bounds__(256) prep_kernel(const float* __restrict__ Phi,
                                                   short* __restrict__ frag,
                                                   float* __restrict__ p2,
                                                   float* __restrict__ p2b) {
    int tid = threadIdx.x;
    {
        const float* p = Phi + tid * DIM;
        float s = 0.f;
#pragma unroll
        for (int d = 0; d < DIM; ++d) s = fmaf(p[d], p[d], s);
        p2[tid] = s;
        p2b[tid] = 256.0f + s;
    }
    for (int it = tid; it < 4096; it += 256) {
        int lane = it & 63;
        int rest = it >> 6;
        int split = rest & 1;
        int ks = (rest >> 1) & 1;
        int ct = rest >> 2;
        int col = lane & 15;
        int kb = ks * 32 + ((lane >> 4) << 3);
        const float* pr = Phi + (ct * 16 + col) * DIM;
        short* dst = frag + (size_t)it * 8;
#pragma unroll
        for (int j = 0; j < 8; ++j) {
            int k = kb + j;
            float v = (k < DIM) ? pr[k] : 0.f;
            short h = f2bf(v);
            dst[j] = (split == 0) ? h : f2bf(v - bf2f(h));
        }
    }
}

// Exact f32 rescreen for one row: identical math/tie-break to the validated scalar kernel.
__device__ void exact_row(const float* __restrict__ X, const float* __restrict__ Phi,
                          const float* __restrict__ p2, int* __restrict__ out, int row) {
    int lane = threadIdx.x & 63;
    const float* xr = X + (size_t)row * DIM;
    float x2 = 0.f;
#pragma unroll
    for (int d = 0; d < DIM; ++d) x2 = fmaf(xr[d], xr[d], x2);
    float best = INFINITY;
    int bi = 0;
    for (int i = 0; i < 4; ++i) {
        int c = lane * 4 + i;                 // within-lane ascending c; strict <
        const float* pr = Phi + c * DIM;
        float a = 0.f;
#pragma unroll
        for (int d = 0; d < DIM; ++d) a = fmaf(xr[d], pr[d], a);
        float sc = (x2 + p2[c]) - 2.0f * a;   // reference rounding order
        if (sc < best) { best = sc; bi = c; }
    }
#pragma unroll
    for (int m = 1; m < 64; m <<= 1) {        // cross-lane: lower idx wins ties
        float ob = __shfl_xor(best, m);
        int oi = __shfl_xor(bi, m);
        if (ob < best || (ob == best && oi < bi)) { best = ob; bi = oi; }
    }
    if (lane == 0) out[row] = bi;
}

__global__ void __launch_bounds__(256, 4) assign_kernel(const float* __restrict__ X,
                                                        const float* __restrict__ Phi,
                                                        const int4* __restrict__ BfI,
                                                        const float* __restrict__ p2,
                                                        const float* __restrict__ p2b,
                                                        int* __restrict__ out) {
    __shared__ int4 Bs[1024];    // 16 KB: quarter of B frags (4 col-tiles) per phase
    __shared__ float P2s[256];   // 1 KB: biased p2

    int tid = threadIdx.x;
    int lane = tid & 63;
    int wid = tid >> 6;
    int t = blockIdx.x * 4 + wid;              // wave tile id: 32 rows each
    bool active = (t < NTILES);
    int tbase = t * (MR * 16);
    int colRow = lane & 15;                    // A: row-within-16; C: col-within-16
    int kgrp = lane >> 4;
    const bf16x8* Bsf = (const bf16x8*)Bs;

    // ---- Stage phase-0 B frags + p2b (all threads; barriers outside `active`) ----
#pragma unroll
    for (int j = 0; j < 4; ++j)
        Bs[tid + j * 256] = BfI[tid + j * 256];
    P2s[tid] = p2b[tid];

    // ---- A-frag load + split (validated path) ----
    bf16x8 Ahi[MR][2], Alo[MR][2];
    unsigned pm1[MR][4], pm2[MR][4];
    if (active) {
#pragma unroll
        for (int mr = 0; mr < MR; ++mr) {
            const float* xp = X + (size_t)(tbase + mr * 16 + colRow) * DIM;
            {   // ks=0: k in [kgrp*8, kgrp*8+8) <= 39 < 50
                float v[8];
                const float2* q = (const float2*)(xp + (kgrp << 3));
#pragma unroll
                for (int h = 0; h < 4; ++h) { float2 e = q[h]; v[2 * h] = e.x; v[2 * h + 1] = e.y; }
                cvt8(v, Ahi[mr][0], Alo[mr][0]);
            }
            {   // ks=1: o = 32+kgrp*8+2h; clamp load in-row, mask o>48
                float v[8];
#pragma unroll
                for (int h = 0; h < 4; ++h) {
                    int o = 32 + (kgrp << 3) + 2 * h;
                    int oc = (o <= 48) ? o : 48;
                    float2 e = *(const float2*)(xp + oc);
                    bool valid = (o <= 48);
                    v[2 * h]     = valid ? e.x : 0.f;
                    v[2 * h + 1] = valid ? e.y : 0.f;
                }
                cvt8(v, Ahi[mr][1], Alo[mr][1]);
            }
        }
#pragma unroll
        for (int mr = 0; mr < MR; ++mr)
#pragma unroll
            for (int r = 0; r < 4; ++r) { pm1[mr][r] = 0xFFFFFFFFu; pm2[mr][r] = 0xFFFFFFFFu; }
    }

    // ---- Per-phase 4-ct loop: scores packed (score&~255 | idx), sorted-pair min ----
    auto process4 = [&](int phase) {
#pragma unroll
        for (int c4 = 0; c4 < 4; ++c4) {
            int ct = phase * 4 + c4;
            bf16x8 b0h = Bsf[(c4 * 4 + 0) * 64 + lane];
            bf16x8 b0l = Bsf[(c4 * 4 + 1) * 64 + lane];
            bf16x8 b1h = Bsf[(c4 * 4 + 2) * 64 + lane];
            bf16x8 b1l = Bsf[(c4 * 4 + 3) * 64 + lane];
            float p2v = P2s[ct * 16 + colRow];
            unsigned vidx = (unsigned)(ct * 16 + colRow);
#pragma unroll
            for (int mr = 0; mr < MR; ++mr) {
                f32x4 acc = {0.f, 0.f, 0.f, 0.f};
                acc = __builtin_amdgcn_mfma_f32_16x16x32_bf16(Alo[mr][0], b0h, acc, 0, 0, 0);
                acc = __builtin_amdgcn_mfma_f32_16x16x32_bf16(Ahi[mr][0], b0l, acc, 0, 0, 0);
                acc = __builtin_amdgcn_mfma_f32_16x16x32_bf16(Ahi[mr][0], b0h, acc, 0, 0, 0);
                acc = __builtin_amdgcn_mfma_f32_16x16x32_bf16(Alo[mr][1], b1h, acc, 0, 0, 0);
                acc = __builtin_amdgcn_mfma_f32_16x16x32_bf16(Ahi[mr][1], b1l, acc, 0, 0, 0);
                acc = __builtin_amdgcn_mfma_f32_16x16x32_bf16(Ahi[mr][1], b1h, acc, 0, 0, 0);
#pragma unroll
                for (int r = 0; r < 4; ++r) {
                    float sc = fmaf(-2.0f, acc[r], p2v);          // positive: bias 256
                    unsigned u = (__builtin_bit_cast(unsigned, sc) & ~255u) | vidx;
                    unsigned u2 = max(pm1[mr][r], u);             // old pm1
                    pm2[mr][r] = min(pm2[mr][r], u2);
                    pm1[mr][r] = min(pm1[mr][r], u);
                }
            }
        }
    };

    __syncthreads();
#pragma unroll
    for (int p = 0; p < 4; ++p) {
        if (active) process4(p);
        __syncthreads();
        if (p < 3) {
#pragma unroll
            for (int j = 0; j < 4; ++j)
                Bs[tid + j * 256] = BfI[(p + 1) * 1024 + tid + j * 256];
            __syncthreads();
        }
    }

    // ---- Epilogue: merge sorted pairs across the 16-lane group; store or rescreen ----
    if (active) {
#pragma unroll
        for (int mr = 0; mr < MR; ++mr) {
#pragma unroll
            for (int r = 0; r < 4; ++r) {
                unsigned a1 = pm1[mr][r], a2 = pm2[mr][r];
#pragma unroll
                for (int m = 1; m <= 8; m <<= 1) {
                    unsigned b1 = (unsigned)__shfl_xor((int)a1, m);
                    unsigned b2 = (unsigned)__shfl_xor((int)a2, m);
                    a2 = min(min(a2, b2), max(a1, b1));
                    a1 = min(a1, b1);
                }
                float f1 = __builtin_bit_cast(float, a1 & ~255u);
                float f2 = __builtin_bit_cast(float, a2 & ~255u);
                bool flag = (f2 - f1) < TAU;          // uniform across the group
                int bi = (int)(a1 & 255u);
                if ((lane & 15) == 0 && !flag)
                    out[tbase + mr * 16 + (lane >> 4) * 4 + r] = bi;
                unsigned long long mb = __ballot(flag) & 0x0001000100010001ULL;
                while (mb) {                           // ~1% of rows: exact rescreen
                    int g = __builtin_ctzll(mb) >> 4;
                    mb &= mb - 1;
                    exact_row(X, Phi, p2, out, tbase + mr * 16 + g * 4 + r);
                }
            }
        }
    }
}

extern "C" void kernel_launch(void* const* d_in, const int* in_sizes, int n_in,
                              void* d_out, int out_size, void* d_ws, size_t ws_size,
                              hipStream_t stream) {
    const float* X   = (const float*)d_in[0];
    const float* Phi = (const float*)d_in[1];
    int* out   = (int*)d_out;
    short* frag = (short*)d_ws;                         // 64 KB
    float* p2   = (float*)((char*)d_ws + 65536);        // 1 KB plain
    float* p2b  = (float*)((char*)d_ws + 65536 + 1024); // 1 KB biased

    prep_kernel<<<1, 256, 0, stream>>>(Phi, frag, p2, p2b);
    int nblk = (NTILES + 3) / 4;                        // 7813 blocks x 256 threads
    assign_kernel<<<nblk, 256, 0, stream>>>(X, Phi, (const int4*)frag, p2, p2b, out);
}